// Round 10
// baseline (323.426 us; speedup 1.0000x reference)
//
#include <hip/hip_runtime.h>

// Problem constants (fixed by the reference)
#define Bn   4
#define Tn   512
#define Pn   3
#define HIDn 512
#define HDn  32
#define Hn   16
#define EXPn 512
#define Sn   1024
#define Dn   96          // per-head dim = P*HD
#define LOG2E 1.44269504088896340736f
#define CH   32          // s-cols per chunk
#define NCH  (Sn / CH)   // 32 chunks

// prep-kernel block ranges
#define NBLK_QK (Bn * Sn)                      // 4096
#define NBLK_V  (Bn * Hn * 16)                 // 1024
#define NBLK_W  ((HIDn * HIDn) / (256 * 8))    // 128
#define NBLK_LW ((Bn * Tn * Sn) / (256 * 8))   // 1024

typedef __bf16 bf16_t;
typedef __bf16 bf16x8 __attribute__((ext_vector_type(8)));
typedef __bf16 bf16x4 __attribute__((ext_vector_type(4)));
typedef float  f32x4  __attribute__((ext_vector_type(4)));

#define GLDS(g, l) __builtin_amdgcn_global_load_lds(                            \
    (const __attribute__((address_space(1))) void*)(g),                         \
    (__attribute__((address_space(3))) void*)(l), 16, 0, 0)

// ---------------------------------------------------------------------------
// prep: fused pack_qk + pack_v + pack_w + lw-mask-pack + sumsq-zero.
// (R13-verified bodies; new 4th range packs lw -> masked bf16 Lb:
//  Lb = (lw <= 1e-5) ? 0 : bf16(lw).  Mask decided in f32 EXACTLY as the
//  reference, so no cutoff-flip risk; bf16 only affects the p*lw multiply.)
//   blocks [0, 4096)        : pack_qk  (192 active threads of 256)
//   blocks [4096, 5120)     : pack_v
//   blocks [5120, 5248)     : pack_w  (+ block 5120 zeroes sumsq)
//   blocks [5248, 6272)     : lw -> Lb bf16
// ---------------------------------------------------------------------------
__global__ __launch_bounds__(256) void prep(
    const float* __restrict__ q, const float* __restrict__ k,
    const float* __restrict__ v, const int* __restrict__ outcell,
    const float* __restrict__ W, const float* __restrict__ lw,
    bf16_t* __restrict__ Qh, bf16_t* __restrict__ Kh,
    bf16_t* __restrict__ Vt, bf16_t* __restrict__ Wb,
    bf16_t* __restrict__ Lb, float* __restrict__ sumsq)
{
    const int blk = blockIdx.x;
    const int tid = threadIdx.x;
    __shared__ float tile[64 * 108];
    __shared__ int ts_sh[64];

    if (blk < NBLK_QK) {
        if (tid < 192) {
            const int b = blk >> 10, s = blk & 1023;
            const int ts = (s < Tn) ? s : outcell[b * EXPn + (s - Tn)];
            const int o = tid;
            const int h = o / 12, c = o % 12;
            const int p = c >> 2, f = c & 3;
            const int src = p * HIDn + h * HDn + f * 8;

            {
                const float* krow = k + (size_t)(b * Tn + ts) * (Pn * HIDn);
                const float4* s4 = (const float4*)(krow + src);
                float4 f0 = s4[0], f1 = s4[1];
                bf16_t o8[8] = {(bf16_t)f0.x, (bf16_t)f0.y, (bf16_t)f0.z, (bf16_t)f0.w,
                                (bf16_t)f1.x, (bf16_t)f1.y, (bf16_t)f1.z, (bf16_t)f1.w};
                *(uint4*)&Kh[(((size_t)b * Hn + h) * Sn + s) * Dn + c * 8] = *(uint4*)o8;
            }
            if (s < Tn) {
                const float* qrow = q + (size_t)(b * Tn + s) * (Pn * HIDn);
                const float4* s4 = (const float4*)(qrow + src);
                float4 f0 = s4[0], f1 = s4[1];
                bf16_t o8[8] = {(bf16_t)(f0.x * LOG2E), (bf16_t)(f0.y * LOG2E),
                                (bf16_t)(f0.z * LOG2E), (bf16_t)(f0.w * LOG2E),
                                (bf16_t)(f1.x * LOG2E), (bf16_t)(f1.y * LOG2E),
                                (bf16_t)(f1.z * LOG2E), (bf16_t)(f1.w * LOG2E)};
                *(uint4*)&Qh[(((size_t)b * Hn + h) * Tn + s) * Dn + c * 8] = *(uint4*)o8;
            }
        }
    } else if (blk < NBLK_QK + NBLK_V) {
        const int vblk = blk - NBLK_QK;
        const int bh = vblk >> 4, s0 = (vblk & 15) << 6;
        const int b = bh >> 4, h = bh & 15;
        if (tid < 64) {
            const int s = s0 + tid;
            ts_sh[tid] = (s < Tn) ? s : outcell[b * EXPn + (s - Tn)];
        }
        __syncthreads();
        for (int u = tid; u < 64 * 24; u += 256) {
            const int sl = u / 24, c = u % 24;
            const int p = c >> 3, f = c & 7;
            float4 val = *(const float4*)&v[(size_t)(b * Tn + ts_sh[sl]) * (Pn * HIDn)
                                            + p * HIDn + h * HDn + f * 4];
            *(float4*)&tile[sl * 108 + c * 4] = val;
        }
        __syncthreads();
        for (int e = tid; e < 96 * 8; e += 256) {
            const int d = e >> 3, g = e & 7;
            bf16_t o8[8];
#pragma unroll
            for (int j = 0; j < 8; ++j) o8[j] = (bf16_t)tile[(g * 8 + j) * 108 + d];
            *(uint4*)&Vt[((size_t)bh * Dn + d) * Sn + s0 + g * 8] = *(uint4*)o8;
        }
    } else if (blk < NBLK_QK + NBLK_V + NBLK_W) {
        const int wblk = blk - (NBLK_QK + NBLK_V);
        const int i = wblk * 256 + tid;
        float4 f0 = *(const float4*)&W[i * 8];
        float4 f1 = *(const float4*)&W[i * 8 + 4];
        bf16_t o8[8] = {(bf16_t)f0.x, (bf16_t)f0.y, (bf16_t)f0.z, (bf16_t)f0.w,
                        (bf16_t)f1.x, (bf16_t)f1.y, (bf16_t)f1.z, (bf16_t)f1.w};
        *(uint4*)&Wb[i * 8] = *(uint4*)o8;
        if (wblk == 0) {
            float4 z = float4{0.f, 0.f, 0.f, 0.f};
            *(float4*)&sumsq[tid * 8]     = z;
            *(float4*)&sumsq[tid * 8 + 4] = z;
        }
    } else {
        // lw (f32) -> Lb (bf16, pre-masked): 8 elems/thread
        const int w2 = blk - (NBLK_QK + NBLK_V + NBLK_W);
        const size_t i = ((size_t)w2 * 256 + tid) * 8;
        float4 f0 = *(const float4*)&lw[i];
        float4 f1 = *(const float4*)&lw[i + 4];
        const float m0 = (f0.x <= 1e-5f) ? 0.f : f0.x;
        const float m1 = (f0.y <= 1e-5f) ? 0.f : f0.y;
        const float m2 = (f0.z <= 1e-5f) ? 0.f : f0.z;
        const float m3 = (f0.w <= 1e-5f) ? 0.f : f0.w;
        const float m4 = (f1.x <= 1e-5f) ? 0.f : f1.x;
        const float m5 = (f1.y <= 1e-5f) ? 0.f : f1.y;
        const float m6 = (f1.z <= 1e-5f) ? 0.f : f1.z;
        const float m7 = (f1.w <= 1e-5f) ? 0.f : f1.w;
        bf16_t o8[8] = {(bf16_t)m0, (bf16_t)m1, (bf16_t)m2, (bf16_t)m3,
                        (bf16_t)m4, (bf16_t)m5, (bf16_t)m6, (bf16_t)m7};
        *(uint4*)&Lb[i] = *(uint4*)o8;
    }
}

// ---------------------------------------------------------------------------
// attn_kernel R15: 128-thread blocks (2-wave convoys), 4 blocks/CU.
// R14 post-mortem: depth-3 prefetch (R12, -7us) and setprio (R14, 0) both
// ~null -> the 6500cyc/chunk period (~1000cyc work) is the BARRIER CONVOY:
// two 4-wave barriers x 32 chunks with only 2 independent blocks/CU.  R15
// halves the convoy group (2 waves share K/V staging) and doubles the
// independent streams (grid 1024 x 128thr; LDS 38.5KB -> exactly 4
// blocks/CU).  lw comes pre-masked as bf16 (Lb) to fit the LDS budget and
// cut the HBM stream.  9 GLDS/wave/chunk, issue c+1 at top of c,
// vmcnt(9) steady / vmcnt(0) tail.  MFMA layouts identical to R11-R14.
// ---------------------------------------------------------------------------
__global__ __launch_bounds__(128, 2) void attn_kernel(
    const bf16_t* __restrict__ Qh, const bf16_t* __restrict__ Kh,
    const bf16_t* __restrict__ Vt, const float* __restrict__ bias,
    const bf16_t* __restrict__ Lb, float* __restrict__ attn_out,
    float* __restrict__ sumsq)
{
    const int h  = blockIdx.x;
    const int b  = blockIdx.y >> 4;
    const int t0 = (blockIdx.y & 15) << 5;     // 32 t-rows per block
    const int tid = threadIdx.x;
    const int wv  = tid >> 6;                  // 0..1
    const int lane = tid & 63;
    const int l16 = lane & 15;
    const int quad = lane >> 4;

    __shared__ bf16_t KfS[2][6][512];          // K frags f=ct*3+ks  (12 KB)
    __shared__ bf16_t VfS[2][6][512];          // V frags f=dt       (12 KB)
    __shared__ float  BfS[2][2][2][256];       // bias [slot][wv][ct] (8 KB)
    __shared__ bf16_t LwS[2][2][512];          // lw bf16 [slot][wv]  (4 KB)
    __shared__ bf16_t Ps[2][16 * 40];          // P transpose        (2.5 KB)

    const size_t bh = (size_t)b * Hn + h;
    const int tb = t0 + wv * 16;               // this wave's first t-row

    // Q as B-fragments (col = t = tb + l16), held in regs all kernel
    bf16x8 qf[3];
    {
        const bf16_t* qb = Qh + (bh * Tn + tb + l16) * Dn + quad * 8;
#pragma unroll
        for (int ks = 0; ks < 3; ++ks) qf[ks] = *(const bf16x8*)(qb + ks * 32);
    }
    asm volatile("s_waitcnt vmcnt(0)" ::: "memory");  // exact in-loop counting

    // per-lane global sources; wave wv stages K frags (ct=wv, ks=0..2) and
    // V frags (dt = wv*3 .. wv*3+2), plus its own bias/lw rows
    const float*  gB  = bias + (bh * Tn + tb + l16) * (size_t)Sn + quad * 4;
    const bf16_t* gLw = Lb + ((size_t)b * Tn + tb + l16) * Sn + quad * 8;
    const bf16_t* gK0 = Kh + (bh * Sn + wv * 16 + l16) * (size_t)Dn + 0 * 32 + quad * 8;
    const bf16_t* gK1 = Kh + (bh * Sn + wv * 16 + l16) * (size_t)Dn + 1 * 32 + quad * 8;
    const bf16_t* gK2 = Kh + (bh * Sn + wv * 16 + l16) * (size_t)Dn + 2 * 32 + quad * 8;
    const bf16_t* gV0 = Vt + (bh * Dn + (wv * 3 + 0) * 16 + l16) * (size_t)Sn + quad * 8;
    const bf16_t* gV1 = Vt + (bh * Dn + (wv * 3 + 1) * 16 + l16) * (size_t)Sn + quad * 8;
    const bf16_t* gV2 = Vt + (bh * Dn + (wv * 3 + 2) * 16 + l16) * (size_t)Sn + quad * 8;

    auto stage = [&](int s0, int buf) {
        GLDS(gK0 + (size_t)s0 * Dn, &KfS[buf][wv * 3 + 0][0]);
        GLDS(gK1 + (size_t)s0 * Dn, &KfS[buf][wv * 3 + 1][0]);
        GLDS(gK2 + (size_t)s0 * Dn, &KfS[buf][wv * 3 + 2][0]);
        GLDS(gV0 + s0, &VfS[buf][wv * 3 + 0][0]);
        GLDS(gV1 + s0, &VfS[buf][wv * 3 + 1][0]);
        GLDS(gV2 + s0, &VfS[buf][wv * 3 + 2][0]);
        GLDS(gB + s0,      &BfS[buf][wv][0][0]);
        GLDS(gB + s0 + 16, &BfS[buf][wv][1][0]);
        GLDS(gLw + s0,     &LwS[buf][wv][0]);
    };

    f32x4 Oacc[6];
#pragma unroll
    for (int i = 0; i < 6; ++i) Oacc[i] = f32x4{0.f, 0.f, 0.f, 0.f};
    float lacc = 0.f;

    stage(0, 0);                               // prologue: chunk 0

    for (int c = 0; c < NCH; ++c) {
        const int buf = c & 1;
        // barrier 1: both waves done READING buf^1 -> safe to overwrite
        __builtin_amdgcn_sched_barrier(0);
        __builtin_amdgcn_s_barrier();
        __builtin_amdgcn_sched_barrier(0);
        if (c + 1 < NCH) {
            stage((c + 1) * CH, buf ^ 1);
            asm volatile("s_waitcnt vmcnt(9)" ::: "memory");   // chunk c landed
        } else {
            asm volatile("s_waitcnt vmcnt(0)" ::: "memory");
        }
        // barrier 2: both waves' slices of chunk c are in LDS
        __builtin_amdgcn_s_barrier();
        __builtin_amdgcn_sched_barrier(0);

        // ---- pull bias (f32x4, conflict-free) and lw (bf16x4)
        f32x4 BR[2];
        BR[0] = *(const f32x4*)&BfS[buf][wv][0][lane * 4];
        BR[1] = *(const f32x4*)&BfS[buf][wv][1][lane * 4];
        bf16x4 lw4[2];
#pragma unroll
        for (int ct = 0; ct < 2; ++ct)
            lw4[ct] = *(const bf16x4*)&LwS[buf][wv][((ct * 2 + (quad >> 1)) * 16 + l16) * 8 + (quad & 1) * 4];

        // ---- QK^T swapped: sc[ct][r] = S[s=c*32+ct*16+quad*4+r][t=tb+l16]
        f32x4 sc[2];
        __builtin_amdgcn_s_setprio(1);
#pragma unroll
        for (int ct = 0; ct < 2; ++ct) {
            f32x4 acc = f32x4{0.f, 0.f, 0.f, 0.f};
#pragma unroll
            for (int ks = 0; ks < 3; ++ks) {
                bf16x8 kf = *(const bf16x8*)&KfS[buf][ct * 3 + ks][lane * 8];
                acc = __builtin_amdgcn_mfma_f32_16x16x32_bf16(kf, qf[ks], acc, 0, 0, 0);
            }
            sc[ct] = acc;
        }
        __builtin_amdgcn_s_setprio(0);

        // ---- p = exp2(sc + bias*LOG2E); masked (lw==0) -> exact 0
        float lsum = 0.f;
#pragma unroll
        for (int ct = 0; ct < 2; ++ct) {
            bf16_t o4[4];
#pragma unroll
            for (int r = 0; r < 4; ++r) {
                const float lwf = (float)lw4[ct][r];
                const float wval = __builtin_fmaf(BR[ct][r], LOG2E, sc[ct][r]);
                const float pe = (lwf > 0.f) ? exp2f(wval) : 0.f;
                lsum += pe;
                o4[r] = (bf16_t)(pe * lwf);
            }
            *(uint2*)&Ps[wv][l16 * 40 + ct * 16 + quad * 4] = *(uint2*)o4;
        }
        lacc += lsum;

        // ---- PV swapped: Oacc[dt] += V-frag(16x32) * P-frag
        bf16x8 pb = *(const bf16x8*)&Ps[wv][l16 * 40 + quad * 8];
        __builtin_amdgcn_s_setprio(1);
#pragma unroll
        for (int dt = 0; dt < 6; ++dt) {
            bf16x8 vf = *(const bf16x8*)&VfS[buf][dt][lane * 8];
            Oacc[dt] = __builtin_amdgcn_mfma_f32_16x16x32_bf16(vf, pb, Oacc[dt], 0, 0, 0);
        }
        __builtin_amdgcn_s_setprio(0);
    }

    // ---- finalize: l-reduce (once), O /= l, scatter, sumsq atomics
    lacc += __shfl_xor(lacc, 16);
    lacc += __shfl_xor(lacc, 32);
    const float invl = 1.0f / lacc;
    const int t = tb + l16;
    float ss = 0.f;
#pragma unroll
    for (int dt = 0; dt < 6; ++dt) {
        const int d0 = dt * 16 + quad * 4;
        f32x4 o;
#pragma unroll
        for (int r = 0; r < 4; ++r) {
            o[r] = Oacc[dt][r] * invl;
            ss += o[r] * o[r];
        }
        const int p = d0 >> 5, hd = d0 & 31;
        *(f32x4*)&attn_out[(((size_t)b * Tn + t) * Pn + p) * HIDn + h * HDn + hd] = o;
    }
    ss += __shfl_xor(ss, 16);
    ss += __shfl_xor(ss, 32);
    if (quad == 0) atomicAdd(&sumsq[b * Tn + t], ss);
}

// ---------------------------------------------------------------------------
// out_gemm (LN fused): xln = attn * lnw[k] * rsqrt(sumsq[bt]/512+eps) during
// the LDS stage; 64x64 dbuf MFMA.  (R13-verified BN=64 version; R14's
// BN=128 regressed -- 384 blocks = 1.5/CU ragged makespan vs 768 = 3/CU.)
// ---------------------------------------------------------------------------
__global__ __launch_bounds__(256, 2) void out_gemm(
    const float* __restrict__ attn, const float* __restrict__ sumsq,
    const float* __restrict__ lnwg, const bf16_t* __restrict__ Bw,
    float* __restrict__ out)
{
    const int n0 = blockIdx.x * 64;
    const int m0 = blockIdx.y * 64;
    const int tid = threadIdx.x;
    const int wv = tid >> 6, lane = tid & 63, l16 = lane & 15, quad = lane >> 4;
    __shared__ float lnw_s[HIDn];
    __shared__ float inv_s[64];
    __shared__ bf16_t As[2][64 * 72];
    __shared__ bf16_t Bs[2][64 * 72];

    for (int i = tid; i < HIDn; i += 256) lnw_s[i] = lnwg[i];
    if (tid < 64)
        inv_s[tid] = rsqrtf(sumsq[(m0 + tid) / 3] * (1.0f / HIDn) + 1e-3f);
    __syncthreads();

    const int rowA = tid >> 3, cA = tid & 7;
    const float inv0 = inv_s[rowA], inv1 = inv_s[rowA + 32];

    auto loadT = [&](int k0, float4 (&AF)[2][2], uint4 (&BR)[2], float4 (&LF)[2]) {
        LF[0] = *(const float4*)&lnw_s[k0 + cA * 8];
        LF[1] = *(const float4*)&lnw_s[k0 + cA * 8 + 4];
        AF[0][0] = *(const float4*)&attn[(size_t)(m0 + rowA) * HIDn + k0 + cA * 8];
        AF[0][1] = *(const float4*)&attn[(size_t)(m0 + rowA) * HIDn + k0 + cA * 8 + 4];
        AF[1][0] = *(const float4*)&attn[(size_t)(m0 + rowA + 32) * HIDn + k0 + cA * 8];
        AF[1][1] = *(const float4*)&attn[(size_t)(m0 + rowA + 32) * HIDn + k0 + cA * 8 + 4];
        BR[0] = *(const uint4*)&Bw[(size_t)(n0 + rowA) * HIDn + k0 + cA * 8];
        BR[1] = *(const uint4*)&Bw[(size_t)(n0 + rowA + 32) * HIDn + k0 + cA * 8];
    };
    auto storeT = [&](int buf, float4 (&AF)[2][2], uint4 (&BR)[2], float4 (&LF)[2]) {
#pragma unroll
        for (int j = 0; j < 2; ++j) {
            const float iv = j ? inv1 : inv0;
            bf16_t a8[8] = {(bf16_t)(AF[j][0].x * LF[0].x * iv), (bf16_t)(AF[j][0].y * LF[0].y * iv),
                            (bf16_t)(AF[j][0].z * LF[0].z * iv), (bf16_t)(AF[j][0].w * LF[0].w * iv),
                            (bf16_t)(AF[j][1].x * LF[1].x * iv), (bf16_t)(AF[j][1].y * LF[1].y * iv),
                            (bf16_t)(AF[j][1].z * LF[1].z * iv), (bf16_t)(AF[j][1].w * LF[1].w * iv)};
            *(uint4*)&As[buf][(rowA + j * 32) * 72 + cA * 8] = *(uint4*)a8;
            *(uint4*)&Bs[buf][(rowA + j * 32) * 72 + cA * 8] = BR[j];
        }
    };

    f32x4 acc[4];
#pragma unroll
    for (int i = 0; i < 4; ++i) acc[i] = f32x4{0.f, 0.f, 0.f, 0.f};

    float4 af0[2][2], af1[2][2], lf0[2], lf1[2];
    uint4 br0[2], br1[2];
    loadT(0, af0, br0, lf0);
    storeT(0, af0, br0, lf0);
    __syncthreads();

    auto compute = [&](int buf) {
#pragma unroll
        for (int ks = 0; ks < 2; ++ks) {
            bf16x8 a = *(const bf16x8*)&As[buf][(wv * 16 + l16) * 72 + ks * 32 + quad * 8];
#pragma unroll
            for (int nt = 0; nt < 4; ++nt) {
                bf16x8 bb = *(const bf16x8*)&Bs[buf][(nt * 16 + l16) * 72 + ks * 32 + quad * 8];
                acc[nt] = __builtin_amdgcn_mfma_f32_16x16x32_bf16(a, bb, acc[nt], 0, 0, 0);
            }
        }
    };

    for (int it = 0; it < 8; it += 2) {
        loadT((it + 1) * 64, af1, br1, lf1);
        compute(0);
        storeT(1, af1, br1, lf1);
        __syncthreads();
        const bool pf = (it + 2) < 8;
        if (pf) loadT((it + 2) * 64, af0, br0, lf0);
        compute(1);
        if (pf) storeT(0, af0, br0, lf0);
        __syncthreads();
    }
#pragma unroll
    for (int nt = 0; nt < 4; ++nt)
#pragma unroll
        for (int r = 0; r < 4; ++r) {
            const int m = m0 + wv * 16 + quad * 4 + r;
            const int n = n0 + nt * 16 + l16;
            out[(size_t)m * HIDn + n] = acc[nt][r];
        }
}

// ---------------------------------------------------------------------------
// Workspace: Qh@0 (6291456) | Kh@6291456 (12582912) | Vt@18874368 (12582912) |
// attn@31457280 (12582912) | Wb@44040192 (524288) | sumsq@44564480 (8192) |
// Lb@44572672 (4194304)  -- total 48,766,976
// ---------------------------------------------------------------------------
extern "C" void kernel_launch(void* const* d_in, const int* in_sizes, int n_in,
                              void* d_out, int out_size, void* d_ws, size_t ws_size,
                              hipStream_t stream)
{
    const float* q    = (const float*)d_in[0];
    const float* k    = (const float*)d_in[1];
    const float* v    = (const float*)d_in[2];
    const float* bias = (const float*)d_in[3];
    const int*   outcell = (const int*)d_in[5];
    const float* lw   = (const float*)d_in[6];
    const float* W    = (const float*)d_in[8];
    const float* lnw  = (const float*)d_in[9];
    float* out = (float*)d_out;

    char* ws = (char*)d_ws;
    bf16_t* Qh   = (bf16_t*)(ws);
    bf16_t* Kh   = (bf16_t*)(ws + 6291456);
    bf16_t* Vt   = (bf16_t*)(ws + 18874368);
    float*  attn = (float*)(ws + 31457280);
    bf16_t* Wb   = (bf16_t*)(ws + 44040192);
    float*  sumsq = (float*)(ws + 44564480);
    bf16_t* Lb   = (bf16_t*)(ws + 44572672);

    prep<<<dim3(NBLK_QK + NBLK_V + NBLK_W + NBLK_LW), 256, 0, stream>>>(
        q, k, v, outcell, W, lw, Qh, Kh, Vt, Wb, Lb, sumsq);
    attn_kernel<<<dim3(Hn, 64), 128, 0, stream>>>(Qh, Kh, Vt, bias, Lb, attn, sumsq);
    out_gemm<<<dim3(HIDn / 64, (Bn * Tn * Pn) / 64), 256, 0, stream>>>(attn, sumsq, lnw, Wb, out);
}

// Round 11
// 294.510 us; speedup vs baseline: 1.0982x; 1.0982x over previous
//
#include <hip/hip_runtime.h>

// Problem constants (fixed by the reference)
#define Bn   4
#define Tn   512
#define Pn   3
#define HIDn 512
#define HDn  32
#define Hn   16
#define EXPn 512
#define Sn   1024
#define Dn   96          // per-head dim = P*HD
#define LOG2E 1.44269504088896340736f
#define CH   32          // s-cols per chunk
#define NCH  (Sn / CH)   // 32 chunks

// prep-kernel block ranges
#define NBLK_QK (Bn * Sn)                      // 4096
#define NBLK_V  (Bn * Hn * 16)                 // 1024
#define NBLK_W  ((HIDn * HIDn) / (256 * 8))    // 128

typedef __bf16 bf16_t;
typedef __bf16 bf16x8 __attribute__((ext_vector_type(8)));
typedef float  f32x4  __attribute__((ext_vector_type(4)));

#define GLDS(g, l) __builtin_amdgcn_global_load_lds(                            \
    (const __attribute__((address_space(1))) void*)(g),                         \
    (__attribute__((address_space(3))) void*)(l), 16, 0, 0)

// ---------------------------------------------------------------------------
// prep: fused pack_qk + pack_v + pack_w + sumsq-zero (R13-verified; R15's
// Lb range reverted).  pack_w now folds lnw into Wb (Wb[n,k] = W[n,k] *
// lnw[k]) so out_gemm's A-stage needs no arithmetic.  (Harness lnw = ones
// -> numerically a no-op fold.)
//   blocks [0, 4096)        : pack_qk  (192 active threads of 256)
//   blocks [4096, 5120)     : pack_v
//   blocks [5120, 5248)     : pack_w  (+ block 5120 zeroes sumsq)
// ---------------------------------------------------------------------------
__global__ __launch_bounds__(256) void prep(
    const float* __restrict__ q, const float* __restrict__ k,
    const float* __restrict__ v, const int* __restrict__ outcell,
    const float* __restrict__ W, const float* __restrict__ lnw,
    bf16_t* __restrict__ Qh, bf16_t* __restrict__ Kh,
    bf16_t* __restrict__ Vt, bf16_t* __restrict__ Wb,
    float* __restrict__ sumsq)
{
    const int blk = blockIdx.x;
    const int tid = threadIdx.x;
    __shared__ float tile[64 * 108];
    __shared__ int ts_sh[64];

    if (blk < NBLK_QK) {
        if (tid < 192) {
            const int b = blk >> 10, s = blk & 1023;
            const int ts = (s < Tn) ? s : outcell[b * EXPn + (s - Tn)];
            const int o = tid;
            const int h = o / 12, c = o % 12;
            const int p = c >> 2, f = c & 3;
            const int src = p * HIDn + h * HDn + f * 8;

            {
                const float* krow = k + (size_t)(b * Tn + ts) * (Pn * HIDn);
                const float4* s4 = (const float4*)(krow + src);
                float4 f0 = s4[0], f1 = s4[1];
                bf16_t o8[8] = {(bf16_t)f0.x, (bf16_t)f0.y, (bf16_t)f0.z, (bf16_t)f0.w,
                                (bf16_t)f1.x, (bf16_t)f1.y, (bf16_t)f1.z, (bf16_t)f1.w};
                *(uint4*)&Kh[(((size_t)b * Hn + h) * Sn + s) * Dn + c * 8] = *(uint4*)o8;
            }
            if (s < Tn) {
                const float* qrow = q + (size_t)(b * Tn + s) * (Pn * HIDn);
                const float4* s4 = (const float4*)(qrow + src);
                float4 f0 = s4[0], f1 = s4[1];
                bf16_t o8[8] = {(bf16_t)(f0.x * LOG2E), (bf16_t)(f0.y * LOG2E),
                                (bf16_t)(f0.z * LOG2E), (bf16_t)(f0.w * LOG2E),
                                (bf16_t)(f1.x * LOG2E), (bf16_t)(f1.y * LOG2E),
                                (bf16_t)(f1.z * LOG2E), (bf16_t)(f1.w * LOG2E)};
                *(uint4*)&Qh[(((size_t)b * Hn + h) * Tn + s) * Dn + c * 8] = *(uint4*)o8;
            }
        }
    } else if (blk < NBLK_QK + NBLK_V) {
        const int vblk = blk - NBLK_QK;
        const int bh = vblk >> 4, s0 = (vblk & 15) << 6;
        const int b = bh >> 4, h = bh & 15;
        if (tid < 64) {
            const int s = s0 + tid;
            ts_sh[tid] = (s < Tn) ? s : outcell[b * EXPn + (s - Tn)];
        }
        __syncthreads();
        for (int u = tid; u < 64 * 24; u += 256) {
            const int sl = u / 24, c = u % 24;
            const int p = c >> 3, f = c & 7;
            float4 val = *(const float4*)&v[(size_t)(b * Tn + ts_sh[sl]) * (Pn * HIDn)
                                            + p * HIDn + h * HDn + f * 4];
            *(float4*)&tile[sl * 108 + c * 4] = val;
        }
        __syncthreads();
        for (int e = tid; e < 96 * 8; e += 256) {
            const int d = e >> 3, g = e & 7;
            bf16_t o8[8];
#pragma unroll
            for (int j = 0; j < 8; ++j) o8[j] = (bf16_t)tile[(g * 8 + j) * 108 + d];
            *(uint4*)&Vt[((size_t)bh * Dn + d) * Sn + s0 + g * 8] = *(uint4*)o8;
        }
    } else {
        const int wblk = blk - (NBLK_QK + NBLK_V);
        const int i = wblk * 256 + tid;           // 8-elem group over [512][512]
        const int d0 = (i * 8) & 511;             // k-index of first elem
        float4 f0 = *(const float4*)&W[i * 8];
        float4 f1 = *(const float4*)&W[i * 8 + 4];
        float4 l0 = *(const float4*)&lnw[d0];
        float4 l1 = *(const float4*)&lnw[d0 + 4];
        bf16_t o8[8] = {(bf16_t)(f0.x * l0.x), (bf16_t)(f0.y * l0.y),
                        (bf16_t)(f0.z * l0.z), (bf16_t)(f0.w * l0.w),
                        (bf16_t)(f1.x * l1.x), (bf16_t)(f1.y * l1.y),
                        (bf16_t)(f1.z * l1.z), (bf16_t)(f1.w * l1.w)};
        *(uint4*)&Wb[i * 8] = *(uint4*)o8;
        if (wblk == 0) {
            float4 z = float4{0.f, 0.f, 0.f, 0.f};
            *(float4*)&sumsq[tid * 8]     = z;
            *(float4*)&sumsq[tid * 8 + 4] = z;
        }
    }
}

// ---------------------------------------------------------------------------
// attn_kernel: R12/R14 structure (best measured 86.3us; R15's 2-wave blocks
// regressed and are reverted).  Async-staged pipeline: bias/lw depth-3,
// K/V depth-2, counted vmcnt, swapped-operand MFMA, no-max softmax, Q
// pre-scaled by LOG2E, setprio on MFMA clusters.  CHANGE vs R14: output is
// written as bf16 Xb (consumed by the async out_gemm); sumsq still
// computed from the f32 accumulators.
// ---------------------------------------------------------------------------
__global__ __launch_bounds__(256, 2) void attn_kernel(
    const bf16_t* __restrict__ Qh, const bf16_t* __restrict__ Kh,
    const bf16_t* __restrict__ Vt, const float* __restrict__ bias,
    const float* __restrict__ lw, bf16_t* __restrict__ Xb,
    float* __restrict__ sumsq)
{
    const int h  = blockIdx.x;
    const int b  = blockIdx.y >> 3;
    const int t0 = (blockIdx.y & 7) << 6;
    const int tid = threadIdx.x;
    const int wv  = tid >> 6;
    const int lane = tid & 63;
    const int l16 = lane & 15;
    const int quad = lane >> 4;

    __shared__ bf16_t KfS[2][6][512];     // K frags f=ct*3+ks   (12 KB)
    __shared__ bf16_t VfS[2][6][512];     // V frags f=dt        (12 KB)
    __shared__ float  BfS[3][4][2][256];  // bias [slot][wv][ct] (24 KB)
    __shared__ float  LfS[3][4][2][256];  // lw   [slot][wv][ct] (24 KB)
    __shared__ bf16_t Ps[4][16 * 40];     // P transpose          (5 KB)

    const size_t bh = (size_t)b * Hn + h;
    const int tb = t0 + wv * 16;

    bf16x8 qf[3];
    {
        const bf16_t* qb = Qh + (bh * Tn + tb + l16) * Dn + quad * 8;
#pragma unroll
        for (int ks = 0; ks < 3; ++ks) qf[ks] = *(const bf16x8*)(qb + ks * 32);
    }
    asm volatile("s_waitcnt vmcnt(0)" ::: "memory");

    int kA, kB, two_k, vA, vB;
    if (wv == 0)      { kA = 0; kB = 1; two_k = 1; vA = 0; vB = 0; }
    else if (wv == 1) { kA = 2; kB = 3; two_k = 1; vA = 1; vB = 0; }
    else if (wv == 2) { kA = 4; kB = 4; two_k = 0; vA = 2; vB = 3; }
    else              { kA = 5; kB = 5; two_k = 0; vA = 4; vB = 5; }

    const float*  gB = bias + (bh * Tn + tb + l16) * (size_t)Sn + quad * 4;
    const float*  gL = lw + ((size_t)b * Tn + tb + l16) * Sn + quad * 4;
    const bf16_t* gKA = Kh + (bh * Sn + (kA / 3) * 16 + l16) * (size_t)Dn + (kA % 3) * 32 + quad * 8;
    const bf16_t* gKB = Kh + (bh * Sn + (kB / 3) * 16 + l16) * (size_t)Dn + (kB % 3) * 32 + quad * 8;
    const bf16_t* gVA = Vt + (bh * Dn + vA * 16 + l16) * (size_t)Sn + quad * 8;
    const bf16_t* gVB = Vt + (bh * Dn + vB * 16 + l16) * (size_t)Sn + quad * 8;

    auto stage_kv = [&](int s0, int buf) {
        GLDS(gKA + (size_t)s0 * Dn, &KfS[buf][kA][0]);
        if (two_k) GLDS(gKB + (size_t)s0 * Dn, &KfS[buf][kB][0]);
        GLDS(gVA + s0, &VfS[buf][vA][0]);
        if (!two_k) GLDS(gVB + s0, &VfS[buf][vB][0]);
    };
    auto stage_bl = [&](int s0, int slot) {
        GLDS(gB + s0,      &BfS[slot][wv][0][0]);
        GLDS(gB + s0 + 16, &BfS[slot][wv][1][0]);
        GLDS(gL + s0,      &LfS[slot][wv][0][0]);
        GLDS(gL + s0 + 16, &LfS[slot][wv][1][0]);
    };

    f32x4 Oacc[6];
#pragma unroll
    for (int i = 0; i < 6; ++i) Oacc[i] = f32x4{0.f, 0.f, 0.f, 0.f};
    float lacc = 0.f;

    stage_bl(0, 0);
    stage_kv(0, 0);
    stage_bl(CH, 1);

    for (int c = 0; c < NCH; ++c) {
        const int buf = c & 1;
        const int slot = c % 3;
        __builtin_amdgcn_sched_barrier(0);
        __builtin_amdgcn_s_barrier();
        __builtin_amdgcn_sched_barrier(0);
        if (c + 1 < NCH) stage_kv((c + 1) * CH, buf ^ 1);
        if (c + 2 < NCH) stage_bl((c + 2) * CH, (c + 2) % 3);
        if (c < NCH - 2)       asm volatile("s_waitcnt vmcnt(11)" ::: "memory");
        else if (c == NCH - 2) asm volatile("s_waitcnt vmcnt(7)" ::: "memory");
        else                   asm volatile("s_waitcnt vmcnt(0)" ::: "memory");
        __builtin_amdgcn_s_barrier();
        __builtin_amdgcn_sched_barrier(0);

        f32x4 BR[2], LR[2];
        BR[0] = *(const f32x4*)&BfS[slot][wv][0][lane * 4];
        BR[1] = *(const f32x4*)&BfS[slot][wv][1][lane * 4];
        LR[0] = *(const f32x4*)&LfS[slot][wv][0][lane * 4];
        LR[1] = *(const f32x4*)&LfS[slot][wv][1][lane * 4];

        f32x4 sc[2];
        __builtin_amdgcn_s_setprio(1);
#pragma unroll
        for (int ct = 0; ct < 2; ++ct) {
            f32x4 acc = f32x4{0.f, 0.f, 0.f, 0.f};
#pragma unroll
            for (int ks = 0; ks < 3; ++ks) {
                bf16x8 kf = *(const bf16x8*)&KfS[buf][ct * 3 + ks][lane * 8];
                acc = __builtin_amdgcn_mfma_f32_16x16x32_bf16(kf, qf[ks], acc, 0, 0, 0);
            }
            sc[ct] = acc;
        }
        __builtin_amdgcn_s_setprio(0);

        float lsum = 0.f;
#pragma unroll
        for (int ct = 0; ct < 2; ++ct) {
            bf16_t o4[4];
#pragma unroll
            for (int r = 0; r < 4; ++r) {
                const float wval = __builtin_fmaf(BR[ct][r], LOG2E, sc[ct][r]);
                const float pe = (LR[ct][r] <= 1e-5f) ? 0.f : exp2f(wval);
                lsum += pe;
                o4[r] = (bf16_t)(pe * LR[ct][r]);
            }
            *(uint2*)&Ps[wv][l16 * 40 + ct * 16 + quad * 4] = *(uint2*)o4;
        }
        lacc += lsum;

        bf16x8 pb = *(const bf16x8*)&Ps[wv][l16 * 40 + quad * 8];
        __builtin_amdgcn_s_setprio(1);
#pragma unroll
        for (int dt = 0; dt < 6; ++dt) {
            bf16x8 vf = *(const bf16x8*)&VfS[buf][dt][lane * 8];
            Oacc[dt] = __builtin_amdgcn_mfma_f32_16x16x32_bf16(vf, pb, Oacc[dt], 0, 0, 0);
        }
        __builtin_amdgcn_s_setprio(0);
    }

    lacc += __shfl_xor(lacc, 16);
    lacc += __shfl_xor(lacc, 32);
    const float invl = 1.0f / lacc;
    const int t = tb + l16;
    float ss = 0.f;
#pragma unroll
    for (int dt = 0; dt < 6; ++dt) {
        const int d0 = dt * 16 + quad * 4;
        bf16_t o4[4];
#pragma unroll
        for (int r = 0; r < 4; ++r) {
            const float o = Oacc[dt][r] * invl;
            ss += o * o;
            o4[r] = (bf16_t)o;
        }
        const int p = d0 >> 5, hd = d0 & 31;
        *(uint2*)&Xb[(((size_t)b * Tn + t) * Pn + p) * HIDn + h * HDn + hd] = *(uint2*)o4;
    }
    ss += __shfl_xor(ss, 16);
    ss += __shfl_xor(ss, 32);
    if (quad == 0) atomicAdd(&sumsq[b * Tn + t], ss);
}

// ---------------------------------------------------------------------------
// out_gemm R16: async-staged pure-bf16 GEMM (R11 pattern ported).
// out[m,n] = inv[m] * sum_k Xb[m,k] * Wb[n,k]   (lnw pre-folded into Wb,
// inv = rsqrt(sumsq/512+eps) applied at the f32 accumulator -- identical
// algebra to the old LN-fused version).  Both operands staged fragment-
// layout via global_load_lds: 4 GLDS/wave/chunk, double-buffered, counted
// vmcnt(4), two raw barriers per chunk.  No VGPR round-trip, no LN math in
// the stage path -- removes the load-serialization that made the old
// loadT/storeT version latency-bound.  LDS 32 KB.
// ---------------------------------------------------------------------------
__global__ __launch_bounds__(256, 2) void out_gemm(
    const bf16_t* __restrict__ Xb, const float* __restrict__ sumsq,
    const bf16_t* __restrict__ Wb, float* __restrict__ out)
{
    const int n0 = blockIdx.x * 64;
    const int m0 = blockIdx.y * 64;
    const int tid = threadIdx.x;
    const int wv = tid >> 6, lane = tid & 63, l16 = lane & 15, quad = lane >> 4;

    __shared__ bf16_t Af[2][8][512];   // A frag f = wv*2+ks  (16 KB)
    __shared__ bf16_t Bf[2][8][512];   // B frag f = nt*2+ks  (16 KB)

    // wave wv stages its own 2 A-frags (rows m0+wv*16) and 2 B-frags (nt=wv)
    const bf16_t* gA0 = Xb + (size_t)(m0 + wv * 16 + l16) * HIDn + 0 * 32 + quad * 8;
    const bf16_t* gA1 = Xb + (size_t)(m0 + wv * 16 + l16) * HIDn + 1 * 32 + quad * 8;
    const bf16_t* gB0 = Wb + (size_t)(n0 + wv * 16 + l16) * HIDn + 0 * 32 + quad * 8;
    const bf16_t* gB1 = Wb + (size_t)(n0 + wv * 16 + l16) * HIDn + 1 * 32 + quad * 8;

    auto stage = [&](int kc, int buf) {
        GLDS(gA0 + kc, &Af[buf][wv * 2 + 0][0]);
        GLDS(gA1 + kc, &Af[buf][wv * 2 + 1][0]);
        GLDS(gB0 + kc, &Bf[buf][wv * 2 + 0][0]);
        GLDS(gB1 + kc, &Bf[buf][wv * 2 + 1][0]);
    };

    f32x4 acc[4];
#pragma unroll
    for (int i = 0; i < 4; ++i) acc[i] = f32x4{0.f, 0.f, 0.f, 0.f};

    stage(0, 0);                           // prologue: chunk 0

    for (int c = 0; c < 8; ++c) {          // 8 K-chunks of 64
        const int buf = c & 1;
        __builtin_amdgcn_sched_barrier(0);
        __builtin_amdgcn_s_barrier();
        __builtin_amdgcn_sched_barrier(0);
        if (c + 1 < 8) {
            stage((c + 1) * 64, buf ^ 1);
            asm volatile("s_waitcnt vmcnt(4)" ::: "memory");
        } else {
            asm volatile("s_waitcnt vmcnt(0)" ::: "memory");
        }
        __builtin_amdgcn_s_barrier();
        __builtin_amdgcn_sched_barrier(0);

        __builtin_amdgcn_s_setprio(1);
#pragma unroll
        for (int ks = 0; ks < 2; ++ks) {
            bf16x8 a = *(const bf16x8*)&Af[buf][wv * 2 + ks][lane * 8];
#pragma unroll
            for (int nt = 0; nt < 4; ++nt) {
                bf16x8 bb = *(const bf16x8*)&Bf[buf][nt * 2 + ks][lane * 8];
                acc[nt] = __builtin_amdgcn_mfma_f32_16x16x32_bf16(a, bb, acc[nt], 0, 0, 0);
            }
        }
        __builtin_amdgcn_s_setprio(0);
    }

    // epilogue: inv[m] per output row, coalesced f32 stores
    float invm[4];
#pragma unroll
    for (int r = 0; r < 4; ++r) {
        const int m = m0 + wv * 16 + quad * 4 + r;
        invm[r] = rsqrtf(sumsq[m / 3] * (1.0f / HIDn) + 1e-3f);
    }
#pragma unroll
    for (int nt = 0; nt < 4; ++nt)
#pragma unroll
        for (int r = 0; r < 4; ++r) {
            const int m = m0 + wv * 16 + quad * 4 + r;
            const int n = n0 + nt * 16 + l16;
            out[(size_t)m * HIDn + n] = acc[nt][r] * invm[r];
        }
}

// ---------------------------------------------------------------------------
// Workspace: Qh@0 (6291456) | Kh@6291456 (12582912) | Vt@18874368 (12582912) |
// Xb@31457280 (6291456) | Wb@37748736 (524288) | sumsq@38273024 (8192)
// ---------------------------------------------------------------------------
extern "C" void kernel_launch(void* const* d_in, const int* in_sizes, int n_in,
                              void* d_out, int out_size, void* d_ws, size_t ws_size,
                              hipStream_t stream)
{
    const float* q    = (const float*)d_in[0];
    const float* k    = (const float*)d_in[1];
    const float* v    = (const float*)d_in[2];
    const float* bias = (const float*)d_in[3];
    const int*   outcell = (const int*)d_in[5];
    const float* lw   = (const float*)d_in[6];
    const float* W    = (const float*)d_in[8];
    const float* lnw  = (const float*)d_in[9];
    float* out = (float*)d_out;

    char* ws = (char*)d_ws;
    bf16_t* Qh   = (bf16_t*)(ws);
    bf16_t* Kh   = (bf16_t*)(ws + 6291456);
    bf16_t* Vt   = (bf16_t*)(ws + 18874368);
    bf16_t* Xb   = (bf16_t*)(ws + 31457280);
    bf16_t* Wb   = (bf16_t*)(ws + 37748736);
    float*  sumsq = (float*)(ws + 38273024);

    prep<<<dim3(NBLK_QK + NBLK_V + NBLK_W), 256, 0, stream>>>(
        q, k, v, outcell, W, lnw, Qh, Kh, Vt, Wb, sumsq);
    attn_kernel<<<dim3(Hn, Bn * (Tn / 64)), 256, 0, stream>>>(Qh, Kh, Vt, bias, lw, Xb, sumsq);
    out_gemm<<<dim3(HIDn / 64, (Bn * Tn * Pn) / 64), 256, 0, stream>>>(Xb, sumsq, Wb, out);
}